// Round 1
// 111.805 us; speedup vs baseline: 1.0294x; 1.0294x over previous
//
#include <hip/hip_runtime.h>
#include <hip/hip_bf16.h>

typedef __bf16 bf16x8 __attribute__((ext_vector_type(8)));
typedef float floatx4 __attribute__((ext_vector_type(4)));

#define BATCH 256
#define INDIM 512
#define ODIM 10
#define HTOT 18432
#define NMODEL 128
#define HTILE 64
#define BTILE 64
#define BK 64
#define LSTRIDE 72   // bf16 elems per LDS row (64 data + 8 pad)
#define ACT_CHUNK 4608
#define NJPG (HTOT / 32)   // 576 aligned 32-neuron pairs

__device__ __forceinline__ unsigned pk2(float a, float b) {
    unsigned ua = __float_as_uint(a);
    ua = (ua + 0x7fffu + ((ua >> 16) & 1u)) >> 16;
    unsigned ub = __float_as_uint(b);
    ub = (ub + 0x7fffu + ((ub >> 16) & 1u)) >> 16;
    return ua | (ub << 16);
}

__device__ __forceinline__ float apply_act(float h, int aidx) {
    if (aidx == 0) return fmaxf(h, 0.f);
    if (aidx == 1) return 1.f - 2.f / (1.f + __expf(2.f * h));   // tanh, no-overflow form
    if (aidx == 2) return 1.f / (1.f + __expf(-h));              // sigmoid
    return h;                                                     // identity
}

// grid = (HTOT/HTILE) * (BATCH/BTILE) = 288 * 4 = 1152 blocks, 256 threads.
// Each wave computes 64j x 16b via acc[4] (16x16x32 bf16 MFMA).
// Partial per-(jpg,o,b) sums go to ws (NO atomics): ws[jpg][o][b].
__global__ __launch_bounds__(256, 4) void mlp_kernel(
    const float* __restrict__ x, const float* __restrict__ hidden_w,
    const float* __restrict__ hidden_b, const float* __restrict__ out_w,
    float* __restrict__ ws)
{
    __shared__ unsigned short xs[BTILE * LSTRIDE];   // 9216 B
    __shared__ unsigned short wsx[HTILE * LSTRIDE];  // 9216 B
    __shared__ float wtile[ODIM * HTILE];            // 2560 B, [o][64]
    __shared__ float btile[HTILE];

    const int tid = threadIdx.x;
    const int bid = blockIdx.x;
    // XCD-sibling swizzle: the 4 batch-blocks (bb=0..3) that share one w-tile
    // get bids congruent mod 8 -> same XCD (round-robin dispatch) -> the
    // 128 KB w-tile is L2-filled once per XCD instead of 4x across XCDs.
    const int r8 = bid & 7, t = bid >> 3;            // t = 0..143 within XCD
    const int jb = r8 * 36 + (t >> 2);               // 8 * 36 = 288 j-tiles
    const int bb = t & 3;
    const int j0 = jb * HTILE;
    const int b0 = bb * BTILE;
    const int lane = tid & 63;
    const int wvid = tid >> 6;               // wave id 0..3 -> b-range [16*wvid, 16*wvid+16)
    const int r = lane & 15;
    const int g = lane >> 4;

    // stage out_w tile + bias (epilogue-only; first __syncthreads covers it)
    for (int i = tid; i < ODIM * HTILE; i += 256)
        wtile[i] = out_w[(i >> 6) * HTOT + j0 + (i & 63)];
    if (tid < HTILE) btile[tid] = hidden_b[j0 + tid];

    floatx4 acc[4];
    #pragma unroll
    for (int jt = 0; jt < 4; jt++) acc[jt] = (floatx4)0.f;

    const floatx4* xv  = (const floatx4*)x;
    const floatx4* wv4 = (const floatx4*)hidden_w;

    // per-thread staging coords (constant across K-steps)
    const int f_row[4] = { (tid + 0)   >> 4, (tid + 256) >> 4,
                           (tid + 512) >> 4, (tid + 768) >> 4 };
    const int f_c4 = tid & 15;

    // prologue: prefetch K-step 0 into registers
    floatx4 vx[4], vw[4];
    #pragma unroll
    for (int i = 0; i < 4; i++) {
        vx[i] = xv[(size_t)(b0 + f_row[i]) * (INDIM / 4) + f_c4];
        vw[i] = wv4[(size_t)(j0 + f_row[i]) * (INDIM / 4) + f_c4];
    }

    for (int kk = 0; kk < INDIM; kk += BK) {
        // pack the prefetched fp32 regs -> bf16 LDS tiles
        #pragma unroll
        for (int i = 0; i < 4; i++) {
            *(uint2*)&xs[f_row[i] * LSTRIDE + f_c4 * 4]  =
                make_uint2(pk2(vx[i][0], vx[i][1]), pk2(vx[i][2], vx[i][3]));
            *(uint2*)&wsx[f_row[i] * LSTRIDE + f_c4 * 4] =
                make_uint2(pk2(vw[i][0], vw[i][1]), pk2(vw[i][2], vw[i][3]));
        }
        __syncthreads();

        // prefetch K-step kk+BK into registers; latency hides under MFMA phase
        if (kk + BK < INDIM) {
            const int kq = (kk + BK) >> 2;
            #pragma unroll
            for (int i = 0; i < 4; i++) {
                vx[i] = xv[(size_t)(b0 + f_row[i]) * (INDIM / 4) + kq + f_c4];
                vw[i] = wv4[(size_t)(j0 + f_row[i]) * (INDIM / 4) + kq + f_c4];
            }
        }

        #pragma unroll
        for (int s = 0; s < 2; s++) {
            bf16x8 bfr = *(const bf16x8*)&xs[(wvid * 16 + r) * LSTRIDE + s * 32 + g * 8];
            #pragma unroll
            for (int jt = 0; jt < 4; jt++) {
                bf16x8 af = *(const bf16x8*)&wsx[(jt * 16 + r) * LSTRIDE + s * 32 + g * 8];
                acc[jt] = __builtin_amdgcn_mfma_f32_16x16x32_bf16(af, bfr, acc[jt], 0, 0, 0);
            }
        }
        __syncthreads();
    }

    // Epilogue. D layout: col(b) = lane&15, row(j within 16-tile) = (lane>>4)*4 + reg.
    const int aidx = j0 / ACT_CHUNK;             // uniform per block (4608 % 64 == 0)
    const int b = b0 + wvid * 16 + r;

    #pragma unroll
    for (int jp = 0; jp < 2; jp++) {
        const int jpg = (j0 >> 5) + jp;          // global 32-pair index
        float a[2][4];
        #pragma unroll
        for (int h = 0; h < 2; h++) {
            int jt = jp * 2 + h;
            #pragma unroll
            for (int q = 0; q < 4; q++)
                a[h][q] = apply_act(acc[jt][q] + btile[jt * 16 + g * 4 + q], aidx);
        }
        #pragma unroll
        for (int o = 0; o < ODIM; o++) {
            float p = 0.f;
            #pragma unroll
            for (int h = 0; h < 2; h++) {
                int jt = jp * 2 + h;
                const float* wr = &wtile[o * HTILE + jt * 16 + g * 4];
                p += a[h][0] * wr[0] + a[h][1] * wr[1] + a[h][2] * wr[2] + a[h][3] * wr[3];
            }
            p += __shfl_xor(p, 16, 64);
            p += __shfl_xor(p, 32, 64);
            if (lane < 16)
                ws[((size_t)jpg * ODIM + o) * BATCH + b] = p;   // plain store, one owner
        }
    }
}

// One block per (model, o): 1280 blocks x 256 threads (thread = b).
// Sums the model's 1..8 jp partials + out_b, writes out[b][m][o] once.
__global__ __launch_bounds__(256) void finalize_kernel(
    const float* __restrict__ ws, const float* __restrict__ out_b,
    float* __restrict__ out)
{
    const int mo = blockIdx.x;           // m*ODIM + o
    const int m = mo / ODIM, o = mo - m * ODIM;
    const int b = threadIdx.x;
    // model m -> structure pattern: rep = m/8, idx = m%8, size = 32*(idx+1)
    const int rep = m >> 3, idx = m & 7;
    const int jp0 = rep * 36 + (idx * (idx + 1)) / 2;
    const int cnt = idx + 1;

    float s = out_b[mo];
    for (int c = 0; c < cnt; c++)
        s += ws[((size_t)(jp0 + c) * ODIM + o) * BATCH + b];
    out[((size_t)b * NMODEL + m) * ODIM + o] = s;
}

extern "C" void kernel_launch(void* const* d_in, const int* in_sizes, int n_in,
                              void* d_out, int out_size, void* d_ws, size_t ws_size,
                              hipStream_t stream) {
    const float* x   = (const float*)d_in[0];
    const float* hw  = (const float*)d_in[1];
    const float* hb  = (const float*)d_in[2];
    const float* ow  = (const float*)d_in[3];
    const float* ob  = (const float*)d_in[4];
    float* out = (float*)d_out;
    float* ws  = (float*)d_ws;           // NJPG * ODIM * BATCH * 4 = 5.9 MB

    mlp_kernel<<<(HTOT / HTILE) * (BATCH / BTILE), 256, 0, stream>>>(x, hw, hb, ow, ws);
    finalize_kernel<<<NMODEL * ODIM, 256, 0, stream>>>(ws, ob, out);
}